// Round 8
// baseline (285.085 us; speedup 1.0000x reference)
//
#include <hip/hip_runtime.h>
#include <hip/hip_bf16.h>

// Problem sizes (fixed): B=8, T=2048, H=64, M=32, S=20, E=3, IN=32
#define Bv  8
#define Tv  2048
#define Hv  64
#define Mv  32
#define Sv  20
#define Ev  3
#define INv 32
#define LOG2E 1.44269504088896340736f
#define NBLK 768u

typedef __attribute__((ext_vector_type(8))) _Float16 half8;
typedef __attribute__((ext_vector_type(4))) _Float16 half4v;
typedef __attribute__((ext_vector_type(2))) __fp16 fp16x2;
typedef __attribute__((ext_vector_type(4))) float float4v;

// ---------------------------------------------------------------------------
// R8: ONE kernel, two phases, software grid barrier (plain launch).
// Theory: the runtime writes back + invalidates per-XCD L2s at every kernel
// boundary (required for correctness since wg->XCD mapping is undefined), so
// producer->consumer L2 reuse across dispatches is impossible — that is the
// invariant 8.75 MB / ~150 GB/s / ~59 us attn floor seen in R1-R7. Removing
// the boundary keeps the K/Kl/V planes in their XCD's L2 (same-XCD handoff
// via the b=bid&7 mapping, both phases on the SAME physical block).
// Q never goes to global at all: phase 2 reads it from phase 1's LDS staging.
// Co-residency (barrier safety): 768 blocks = 3/CU; LDS 3x34KB <= 160KB;
// __launch_bounds__(256,3) caps VGPR at 170 -> all blocks resident.
// ---------------------------------------------------------------------------

__global__ void init_bar(unsigned int* c) { *c = 0u; }

#define ATT_LOAD(c, KH, KL, V0, V1)                                           \
    {                                                                         \
        size_t ko = ebOff + (size_t)((c) * 64 + w * 16 + l15) * 32 + quad * 8;\
        KH = *(const half8*)(Kh + ko);                                        \
        KL = *(const half8*)(Kl + ko);                                        \
        size_t vo = ebOff + (size_t)(c) * 2048 + (size_t)l15 * 64             \
                    + w * 16 + quad * 4;                                      \
        V0 = *(const half4v*)(Vth + vo);                                      \
        V1 = *(const half4v*)(Vth + vo + 1024);                               \
    }

#define ATT_BODY(KH, KL, V0, V1)                                              \
    _Pragma("unroll")                                                         \
    for (int qt = 0; qt < 4; ++qt) {                                          \
        float4v acc = {0.f, 0.f, 0.f, 0.f};                                   \
        acc = __builtin_amdgcn_mfma_f32_16x16x32_f16(KH, qL[qt], acc, 0,0,0); \
        acc = __builtin_amdgcn_mfma_f32_16x16x32_f16(KL, qH[qt], acc, 0,0,0); \
        acc = __builtin_amdgcn_mfma_f32_16x16x32_f16(KH, qH[qt], acc, 0,0,0); \
        float pmax4 = fmaxf(fmaxf(acc[0], acc[1]), fmaxf(acc[2], acc[3]));    \
        if (!__any(pmax4 > mm[qt] - 20.0f)) continue;   /* tile irrelevant */ \
        if (__any(pmax4 > mm[qt] + 8.0f)) {             /* rare rescale */    \
            float pm = fmaxf(pmax4, __shfl_xor(pmax4, 16));                   \
            pm = fmaxf(pm, __shfl_xor(pm, 32));                               \
            float mn = fmaxf(mm[qt], pm);                                     \
            float al = exp2f(mm[qt] - mn);                                    \
            mm[qt] = mn;                                                      \
            _Pragma("unroll")                                                 \
            for (int r = 0; r < 4; ++r) {                                     \
                O[qt][0][r] *= al; O[qt][1][r] *= al;                         \
            }                                                                 \
        }                                                                     \
        fp16x2 p01 = __builtin_amdgcn_cvt_pkrtz(exp2f(acc[0] - mm[qt]),       \
                                                exp2f(acc[1] - mm[qt]));      \
        fp16x2 p23 = __builtin_amdgcn_cvt_pkrtz(exp2f(acc[2] - mm[qt]),       \
                                                exp2f(acc[3] - mm[qt]));      \
        unsigned long long up =                                               \
            ((unsigned long long)__builtin_bit_cast(unsigned int, p23) << 32) \
            | __builtin_bit_cast(unsigned int, p01);                          \
        half4v pB = __builtin_bit_cast(half4v, up);                           \
        O[qt][0] = __builtin_amdgcn_mfma_f32_16x16x16f16(V0, pB, O[qt][0],    \
                                                         0, 0, 0);            \
        O[qt][1] = __builtin_amdgcn_mfma_f32_16x16x16f16(V1, pB, O[qt][1],    \
                                                         0, 0, 0);            \
    }

__global__ __launch_bounds__(256, 3) void fused_kernel(
    const float* __restrict__ hidden,
    const float* __restrict__ Wq,
    const float* __restrict__ Wk,
    const float* __restrict__ Wv,
    const float* __restrict__ x,
    const float* __restrict__ memory,
    const float* __restrict__ iq,
    _Float16* __restrict__ Kh, _Float16* __restrict__ Kl,
    _Float16* __restrict__ Vth,
    float* __restrict__ memout,
    float* __restrict__ out,
    unsigned int* __restrict__ bar)
{
    // Arena overlay. Phase1: blob 24576 | sIQ 4096 | sM 2560  (31232 B)
    //                Phase2: sO 33792 | sMw 1024              (34816 B)
    // Q staging (arena[0..8192)) survives into phase2 entry (read before
    // sO's first write, fenced by a __syncthreads).
    __shared__ __align__(16) char arena[34816];

    int bid  = blockIdx.x;              // 768 = E*B*32
    int tid  = threadIdx.x;
    int lane = tid & 63;
    int w    = tid >> 6;
    int quad = lane >> 4;
    int l15  = lane & 15;

    int b    = bid & 7;                 // XCD = b: producer==consumer XCD
    int slot = bid >> 3;
    int tile = slot & 31;
    int e    = slot >> 5;
    size_t eb = (size_t)(e * Bv + b);

    // ======================= PHASE 1: QKV ==================================
    {
        char* sBlob = arena;
        float (*sIQ)[32] = (float (*)[32])(arena + 24576);
        float (*sM)[32]  = (float (*)[32])(arena + 28672);

        size_t row0 = eb * Tv + (size_t)tile * 64;
        const float* hbase = hidden + row0 * Hv;

        const float* arow = hbase + (size_t)(w * 16 + l15) * Hv + quad * 8;
        float4v a0 = __builtin_nontemporal_load((const float4v*)(arow));
        float4v a1 = __builtin_nontemporal_load((const float4v*)(arow + 4));
        float4v a2 = __builtin_nontemporal_load((const float4v*)(arow + 32));
        float4v a3 = __builtin_nontemporal_load((const float4v*)(arow + 36));

        if (e == 0) {
            for (int i = tid; i < 32 * 32; i += 256) sIQ[i >> 5][i & 31] = iq[i];
            for (int i = tid; i < 20 * 32; i += 256) sM[i >> 5][i & 31] = memory[i];
        }

        {
            const float* wsrc[3] = {Wq + (size_t)e * Hv * Mv,
                                    Wk + (size_t)e * Hv * Mv,
                                    Wv + (size_t)e * Hv * Mv};
            int m0 = (tid & 3) * 8;
            int h  = tid >> 2;
            int kb = h >> 3, wi = h & 7;
#pragma unroll
            for (int p = 0; p < 3; ++p) {
                const float4v* src = (const float4v*)(wsrc[p] + (size_t)tid * 8);
                float4v wa = src[0], wb = src[1];
                float wv8[8] = {wa.x, wa.y, wa.z, wa.w, wb.x, wb.y, wb.z, wb.w};
                float scale = (p == 0) ? LOG2E : 1.f;
#pragma unroll
                for (int j = 0; j < 8; ++j) {
                    int c = p * 32 + m0 + j;
                    float v = wv8[j] * scale;
                    _Float16 hh = (_Float16)v;
                    _Float16 ll = (_Float16)(v - (float)hh);
                    int off = c * 128 + ((kb ^ (c & 7)) << 4) + wi * 2;
                    *(_Float16*)(sBlob + off)         = hh;
                    *(_Float16*)(sBlob + 12288 + off) = ll;
                }
            }
        }

        half8 aH0, aL0, aH1, aL1;
        {
            float vv[8] = {a0.x, a0.y, a0.z, a0.w, a1.x, a1.y, a1.z, a1.w};
#pragma unroll
            for (int i = 0; i < 8; ++i) {
                _Float16 hh = (_Float16)vv[i];
                aH0[i] = hh; aL0[i] = (_Float16)(vv[i] - (float)hh);
            }
            float ww[8] = {a2.x, a2.y, a2.z, a2.w, a3.x, a3.y, a3.z, a3.w};
#pragma unroll
            for (int i = 0; i < 8; ++i) {
                _Float16 hh = (_Float16)ww[i];
                aH1[i] = hh; aL1[i] = (_Float16)(ww[i] - (float)hh);
            }
        }

        __syncthreads();

        float4v accs[6];
        int x7 = l15 & 7;
#pragma unroll
        for (int ct = 0; ct < 6; ++ct) {
            const char* brow = sBlob + (ct * 16 + l15) * 128;
            half8 bH0 = *(const half8*)(brow + ((quad ^ x7) << 4));
            half8 bH1 = *(const half8*)(brow + (((4 + quad) ^ x7) << 4));
            half8 bL0 = *(const half8*)(brow + 12288 + ((quad ^ x7) << 4));
            half8 bL1 = *(const half8*)(brow + 12288 + (((4 + quad) ^ x7) << 4));
            float4v acc = {0.f, 0.f, 0.f, 0.f};
            acc = __builtin_amdgcn_mfma_f32_16x16x32_f16(aH0, bL0, acc, 0, 0, 0);
            acc = __builtin_amdgcn_mfma_f32_16x16x32_f16(aL0, bH0, acc, 0, 0, 0);
            acc = __builtin_amdgcn_mfma_f32_16x16x32_f16(aH0, bH0, acc, 0, 0, 0);
            acc = __builtin_amdgcn_mfma_f32_16x16x32_f16(aH1, bL1, acc, 0, 0, 0);
            acc = __builtin_amdgcn_mfma_f32_16x16x32_f16(aL1, bH1, acc, 0, 0, 0);
            acc = __builtin_amdgcn_mfma_f32_16x16x32_f16(aH1, bH1, acc, 0, 0, 0);
            accs[ct] = acc;
        }

        __syncthreads();   // blob reads done; reuse as output staging

        char* sQh = sBlob;
        char* sQl = sBlob + 4096;
        char* sKh = sBlob + 8192;
        char* sKl = sBlob + 12288;
        char* sVh = sBlob + 16384;
        int rbase = w * 16 + quad * 4;
#pragma unroll
        for (int ct = 0; ct < 6; ++ct) {
            int c = ct * 16 + l15;
#pragma unroll
            for (int r = 0; r < 4; ++r) {
                int row = rbase + r;
                float v = accs[ct][r];
                if (ct < 2) {                    // Q: LDS only (phase2 reads it)
                    _Float16 h16 = (_Float16)v;
                    *(_Float16*)(sQh + row * 64 + c * 2) = h16;
                    *(_Float16*)(sQl + row * 64 + c * 2) = (_Float16)(v - (float)h16);
                } else if (ct < 4) {             // K linear hi/lo -> global
                    _Float16 h16 = (_Float16)v;
                    int m = c - 32;
                    int off = row * 64 + m * 2;
                    *(_Float16*)(sKh + off) = h16;
                    *(_Float16*)(sKl + off) = (_Float16)(v - (float)h16);
                } else {                         // V transposed -> global
                    int d = c - 64;
                    int off = d * 128 + row * 2;
                    *(_Float16*)(sVh + off) = (_Float16)v;
                }
            }
        }
        __syncthreads();

        // only K/Kl/V go to global (Q stays in LDS)
        size_t pb = eb * (size_t)Tv * 32 + (size_t)tile * 2048;
        _Float16* dsts[3] = {Kh + pb, Kl + pb, Vth + pb};
#pragma unroll
        for (int pl = 0; pl < 3; ++pl)
            ((float4v*)dsts[pl])[tid] = ((const float4v*)(sBlob + (pl + 2) * 4096))[tid];

        if (e == 0) {
            int tok4 = tid >> 2;
            int m0   = (tid & 3) * 8;
            int t = b * Tv + tile * 64 + tok4;
            const float4v* xr = (const float4v*)(x + (size_t)t * INv);
            float qm[8];
#pragma unroll
            for (int m = 0; m < 8; ++m) qm[m] = 0.f;
#pragma unroll
            for (int i4 = 0; i4 < 8; ++i4) {
                float4v xv = __builtin_nontemporal_load(&xr[i4]);
                float xs[4] = {xv.x, xv.y, xv.z, xv.w};
#pragma unroll
                for (int s = 0; s < 4; ++s) {
                    int i = i4 * 4 + s;
                    float xi = xs[s];
                    float4v w0 = *(const float4v*)&sIQ[i][m0];
                    float4v w1 = *(const float4v*)&sIQ[i][m0 + 4];
                    qm[0] = fmaf(xi, w0.x, qm[0]); qm[1] = fmaf(xi, w0.y, qm[1]);
                    qm[2] = fmaf(xi, w0.z, qm[2]); qm[3] = fmaf(xi, w0.w, qm[3]);
                    qm[4] = fmaf(xi, w1.x, qm[4]); qm[5] = fmaf(xi, w1.y, qm[5]);
                    qm[6] = fmaf(xi, w1.z, qm[6]); qm[7] = fmaf(xi, w1.w, qm[7]);
                }
            }
            float sc[20];
#pragma unroll
            for (int j = 0; j < 20; ++j) {
                float4v s0 = *(const float4v*)&sM[j][m0];
                float4v s1 = *(const float4v*)&sM[j][m0 + 4];
                float a2 = qm[0]*s0.x + qm[1]*s0.y + qm[2]*s0.z + qm[3]*s0.w
                         + qm[4]*s1.x + qm[5]*s1.y + qm[6]*s1.z + qm[7]*s1.w;
                a2 += __shfl_xor(a2, 1);
                a2 += __shfl_xor(a2, 2);
                sc[j] = a2;
            }
            float mx = sc[0];
#pragma unroll
            for (int j = 1; j < 20; ++j) mx = fmaxf(mx, sc[j]);
            float psum = 0.f, p[20];
#pragma unroll
            for (int j = 0; j < 20; ++j) { p[j] = exp2f((sc[j] - mx) * LOG2E); psum += p[j]; }
            float inv = 1.0f / psum;
            float mo[8];
#pragma unroll
            for (int m = 0; m < 8; ++m) mo[m] = 0.f;
#pragma unroll
            for (int j = 0; j < 20; ++j) {
                float pj = p[j];
                float4v s0 = *(const float4v*)&sM[j][m0];
                float4v s1 = *(const float4v*)&sM[j][m0 + 4];
                mo[0] = fmaf(pj, s0.x, mo[0]); mo[1] = fmaf(pj, s0.y, mo[1]);
                mo[2] = fmaf(pj, s0.z, mo[2]); mo[3] = fmaf(pj, s0.w, mo[3]);
                mo[4] = fmaf(pj, s1.x, mo[4]); mo[5] = fmaf(pj, s1.y, mo[5]);
                mo[6] = fmaf(pj, s1.z, mo[6]); mo[7] = fmaf(pj, s1.w, mo[7]);
            }
            float4v* outp = (float4v*)(memout + (size_t)t * Mv + m0);
            float4v o0 = {mo[0]*inv, mo[1]*inv, mo[2]*inv, mo[3]*inv};
            float4v o1 = {mo[4]*inv, mo[5]*inv, mo[6]*inv, mo[7]*inv};
            outp[0] = o0;
            outp[1] = o1;
        }
    }

    // ================= SOFTWARE GRID BARRIER (all 768 co-resident) =========
    __syncthreads();                    // drains this block's stores (vmcnt)
    if (tid == 0) {
        __threadfence();                // release plane/memout writes
        __hip_atomic_fetch_add(bar, 1u, __ATOMIC_ACQ_REL, __HIP_MEMORY_SCOPE_AGENT);
        int guard = 0;
        while (__hip_atomic_load(bar, __ATOMIC_ACQUIRE, __HIP_MEMORY_SCOPE_AGENT)
                   < NBLK && guard < 100000000) {
            __builtin_amdgcn_s_sleep(16);
            ++guard;
        }
    }
    __syncthreads();
    __threadfence();                    // acquire: invalidate this CU's L1

    // ======================= PHASE 2: ATTN =================================
    {
        size_t ebOff = eb * (size_t)Tv * 32;

        // Q fragments from phase1's LDS staging (never touched global)
        half8 qH[4], qL[4];
        {
            const char* sQh = arena;
            const char* sQl = arena + 4096;
#pragma unroll
            for (int qt = 0; qt < 4; ++qt) {
                int off = (qt * 16 + l15) * 64 + quad * 16;
                qH[qt] = *(const half8*)(sQh + off);
                qL[qt] = *(const half8*)(sQl + off);
            }
        }
        __syncthreads();                // Q reads done before sO overwrites

        float (*sO)[64][33] = (float (*)[64][33])arena;
        float (*sMw)[64]    = (float (*)[64])(arena + 33792);

        float4v O[4][2];
#pragma unroll
        for (int qt = 0; qt < 4; ++qt) {
            O[qt][0] = {0.f, 0.f, 0.f, 0.f};
            O[qt][1] = {0.f, 0.f, 0.f, 0.f};
        }
        float mm[4] = {-3.0e38f, -3.0e38f, -3.0e38f, -3.0e38f};

        half8 kHa, kLa, kHb, kLb;
        half4v v0a, v1a, v0b, v1b;
        ATT_LOAD(0, kHa, kLa, v0a, v1a);

        for (int c = 0; c < 32; c += 2) {
            ATT_LOAD(c + 1, kHb, kLb, v0b, v1b);
            ATT_BODY(kHa, kLa, v0a, v1a);
            if (c + 2 < 32) ATT_LOAD(c + 2, kHa, kLa, v0a, v1a);
            ATT_BODY(kHb, kLb, v0b, v1b);
        }

#pragma unroll
        for (int qt = 0; qt < 4; ++qt) {
            int q = qt * 16 + l15;
            sMw[w][q] = mm[qt];
#pragma unroll
            for (int dh = 0; dh < 2; ++dh)
#pragma unroll
                for (int r = 0; r < 4; ++r)
                    sO[w][q][dh * 16 + quad * 4 + r] = O[qt][dh][r];
        }
        __syncthreads();

        int q  = tid >> 2;
        int dq = tid & 3;
        float ms0 = sMw[0][q], ms1 = sMw[1][q], ms2 = sMw[2][q], ms3 = sMw[3][q];
        float M  = fmaxf(fmaxf(ms0, ms1), fmaxf(ms2, ms3));
        float g0 = exp2f(ms0 - M), g1 = exp2f(ms1 - M);
        float g2 = exp2f(ms2 - M), g3 = exp2f(ms3 - M);
        const float* mb = memout + ((size_t)b * Tv + tile * 64 + q) * 32 + dq * 8;
        float dotm = 0.f, oo = 0.f, mm2 = 0.f;
#pragma unroll
        for (int j = 0; j < 8; ++j) {
            int d = dq * 8 + j;
            float o = g0 * sO[0][q][d] + g1 * sO[1][q][d]
                    + g2 * sO[2][q][d] + g3 * sO[3][q][d];
            float mvv = mb[j];
            dotm = fmaf(o, mvv, dotm);
            oo   = fmaf(o, o, oo);
            mm2  = fmaf(mvv, mvv, mm2);
        }
        dotm += __shfl_xor(dotm, 1); dotm += __shfl_xor(dotm, 2);
        oo   += __shfl_xor(oo, 1);   oo   += __shfl_xor(oo, 2);
        mm2  += __shfl_xor(mm2, 1);  mm2  += __shfl_xor(mm2, 2);
        if (dq == 0) {
            float na = fmaxf(sqrtf(mm2), 1e-8f);
            float nb = fmaxf(sqrtf(oo), 1e-30f);
            out[((size_t)b * Tv + tile * 64 + q) * Ev + e] = dotm / (na * nb);
        }
    }
}

// ---------------------------------------------------------------------------
extern "C" void kernel_launch(void* const* d_in, const int* in_sizes, int n_in,
                              void* d_out, int out_size, void* d_ws, size_t ws_size,
                              hipStream_t stream) {
    const float* x      = (const float*)d_in[0];
    const float* hidden = (const float*)d_in[1];
    const float* memory = (const float*)d_in[2];
    const float* Wq     = (const float*)d_in[3];
    const float* Wk     = (const float*)d_in[4];
    const float* Wv     = (const float*)d_in[5];
    const float* iq     = (const float*)d_in[6];
    float* out          = (float*)d_out;           // [B,T,E] fp32

    char* ws = (char*)d_ws;
    // layout (bytes): memout f32 (2 MiB) | barrier (in old Qh slot) |
    //                 Kh/Kl/Vth planes at their historical offsets.
    const size_t PLANE = (size_t)Ev * Bv * Tv * 32 * 2;   // 3,145,728 B
    float*        memout = (float*)ws;
    unsigned int* bar    = (unsigned int*)(ws + 2097152);        // Qh slot (unused)
    _Float16* Kh  = (_Float16*)(ws + 2097152 + 2 * PLANE);
    _Float16* Kl  = (_Float16*)(ws + 2097152 + 3 * PLANE);
    _Float16* Vth = (_Float16*)(ws + 2097152 + 4 * PLANE);

    init_bar<<<1, 1, 0, stream>>>(bar);
    fused_kernel<<<Ev * Bv * (Tv / 64), 256, 0, stream>>>(
        hidden, Wq, Wk, Wv, x, memory, iq,
        Kh, Kl, Vth, memout, out, bar);
}

// Round 9
// 136.171 us; speedup vs baseline: 2.0936x; 2.0936x over previous
//
#include <hip/hip_runtime.h>
#include <hip/hip_bf16.h>

// Problem sizes (fixed): B=8, T=2048, H=64, M=32, S=20, E=3, IN=32
#define Bv  8
#define Tv  2048
#define Hv  64
#define Mv  32
#define Sv  20
#define Ev  3
#define INv 32
#define LOG2E 1.44269504088896340736f

typedef __attribute__((ext_vector_type(8))) _Float16 half8;
typedef __attribute__((ext_vector_type(4))) _Float16 half4v;
typedef __attribute__((ext_vector_type(2))) __fp16 fp16x2;
typedef __attribute__((ext_vector_type(4))) float float4v;

// ---------------------------------------------------------------------------
// Kernel 1: MFMA QKV + fused memories (R5 verbatim — best measured: 134.26us
// total). R6 (cooperative fusion) crashed the harness; R8 (software-barrier
// fusion) regressed to 238us/dispatch. Two-kernel structure is the winner.
// Plane formats (consumed by attn):
//   Qh/Ql : linear [token][32]  (pre-scaled by LOG2E via Wq)
//   Kh/Kl : linear [token][32]
//   Vth   : per 64-token tile: [d=0..31][k=0..63]  (transposed, linear)
// ---------------------------------------------------------------------------
__global__ __launch_bounds__(256) void qkv_kernel(
    const float* __restrict__ hidden,
    const float* __restrict__ Wq,
    const float* __restrict__ Wk,
    const float* __restrict__ Wv,
    const float* __restrict__ x,        // [B*T, 32] for fused mem
    const float* __restrict__ memory,   // [20, 32]
    const float* __restrict__ iq,       // [32, 32]
    _Float16* __restrict__ Qh, _Float16* __restrict__ Ql,
    _Float16* __restrict__ Kh, _Float16* __restrict__ Kl,
    _Float16* __restrict__ Vth,
    float* __restrict__ memout)         // [B*T, 32]
{
    __shared__ __align__(16) char sBlob[24576];
    __shared__ float sIQ[32][32];
    __shared__ float sM[20][32];

    int bid  = blockIdx.x;              // 768 = E*B*32
    int b    = bid & 7;                 // XCD = b (match attn consumer)
    int slot = bid >> 3;
    int tile = slot & 31;
    int e    = slot >> 5;
    int tid  = threadIdx.x;
    int lane = tid & 63;
    int w    = tid >> 6;
    int quad = lane >> 4;
    int l15  = lane & 15;
    size_t eb = (size_t)(e * Bv + b);
    size_t row0 = eb * Tv + (size_t)tile * 64;
    const float* hbase = hidden + row0 * Hv;

    const float* arow = hbase + (size_t)(w * 16 + l15) * Hv + quad * 8;
    float4v a0 = __builtin_nontemporal_load((const float4v*)(arow));
    float4v a1 = __builtin_nontemporal_load((const float4v*)(arow + 4));
    float4v a2 = __builtin_nontemporal_load((const float4v*)(arow + 32));
    float4v a3 = __builtin_nontemporal_load((const float4v*)(arow + 36));

    if (e == 0) {
        for (int i = tid; i < 32 * 32; i += 256) sIQ[i >> 5][i & 31] = iq[i];
        for (int i = tid; i < 20 * 32; i += 256) sM[i >> 5][i & 31] = memory[i];
    }

    {
        const float* wsrc[3] = {Wq + (size_t)e * Hv * Mv,
                                Wk + (size_t)e * Hv * Mv,
                                Wv + (size_t)e * Hv * Mv};
        int m0 = (tid & 3) * 8;
        int h  = tid >> 2;
        int kb = h >> 3, wi = h & 7;
#pragma unroll
        for (int p = 0; p < 3; ++p) {
            const float4v* src = (const float4v*)(wsrc[p] + (size_t)tid * 8);
            float4v wa = src[0], wb = src[1];
            float wv8[8] = {wa.x, wa.y, wa.z, wa.w, wb.x, wb.y, wb.z, wb.w};
            float scale = (p == 0) ? LOG2E : 1.f;
#pragma unroll
            for (int j = 0; j < 8; ++j) {
                int c = p * 32 + m0 + j;
                float v = wv8[j] * scale;
                _Float16 hh = (_Float16)v;
                _Float16 ll = (_Float16)(v - (float)hh);
                int off = c * 128 + ((kb ^ (c & 7)) << 4) + wi * 2;
                *(_Float16*)(sBlob + off)         = hh;
                *(_Float16*)(sBlob + 12288 + off) = ll;
            }
        }
    }

    half8 aH0, aL0, aH1, aL1;
    {
        float vv[8] = {a0.x, a0.y, a0.z, a0.w, a1.x, a1.y, a1.z, a1.w};
#pragma unroll
        for (int i = 0; i < 8; ++i) {
            _Float16 hh = (_Float16)vv[i];
            aH0[i] = hh; aL0[i] = (_Float16)(vv[i] - (float)hh);
        }
        float ww[8] = {a2.x, a2.y, a2.z, a2.w, a3.x, a3.y, a3.z, a3.w};
#pragma unroll
        for (int i = 0; i < 8; ++i) {
            _Float16 hh = (_Float16)ww[i];
            aH1[i] = hh; aL1[i] = (_Float16)(ww[i] - (float)hh);
        }
    }

    __syncthreads();

    float4v accs[6];
    int x7 = l15 & 7;
#pragma unroll
    for (int ct = 0; ct < 6; ++ct) {
        const char* brow = sBlob + (ct * 16 + l15) * 128;
        half8 bH0 = *(const half8*)(brow + ((quad ^ x7) << 4));
        half8 bH1 = *(const half8*)(brow + (((4 + quad) ^ x7) << 4));
        half8 bL0 = *(const half8*)(brow + 12288 + ((quad ^ x7) << 4));
        half8 bL1 = *(const half8*)(brow + 12288 + (((4 + quad) ^ x7) << 4));
        float4v acc = {0.f, 0.f, 0.f, 0.f};
        acc = __builtin_amdgcn_mfma_f32_16x16x32_f16(aH0, bL0, acc, 0, 0, 0);
        acc = __builtin_amdgcn_mfma_f32_16x16x32_f16(aL0, bH0, acc, 0, 0, 0);
        acc = __builtin_amdgcn_mfma_f32_16x16x32_f16(aH0, bH0, acc, 0, 0, 0);
        acc = __builtin_amdgcn_mfma_f32_16x16x32_f16(aH1, bL1, acc, 0, 0, 0);
        acc = __builtin_amdgcn_mfma_f32_16x16x32_f16(aL1, bH1, acc, 0, 0, 0);
        acc = __builtin_amdgcn_mfma_f32_16x16x32_f16(aH1, bH1, acc, 0, 0, 0);
        accs[ct] = acc;
    }

    __syncthreads();

    char* sQh = sBlob;
    char* sQl = sBlob + 4096;
    char* sKh = sBlob + 8192;
    char* sKl = sBlob + 12288;
    char* sVh = sBlob + 16384;
    int rbase = w * 16 + quad * 4;
#pragma unroll
    for (int ct = 0; ct < 6; ++ct) {
        int c = ct * 16 + l15;
#pragma unroll
        for (int r = 0; r < 4; ++r) {
            int row = rbase + r;
            float v = accs[ct][r];
            if (ct < 2) {
                _Float16 h16 = (_Float16)v;
                *(_Float16*)(sQh + row * 64 + c * 2) = h16;
                *(_Float16*)(sQl + row * 64 + c * 2) = (_Float16)(v - (float)h16);
            } else if (ct < 4) {
                _Float16 h16 = (_Float16)v;
                int m = c - 32;
                int off = row * 64 + m * 2;
                *(_Float16*)(sKh + off) = h16;
                *(_Float16*)(sKl + off) = (_Float16)(v - (float)h16);
            } else {
                int d = c - 64;
                int off = d * 128 + row * 2;
                *(_Float16*)(sVh + off) = (_Float16)v;
            }
        }
    }
    __syncthreads();

    size_t pb = eb * (size_t)Tv * 32 + (size_t)tile * 2048;
    _Float16* dsts[5] = {Qh + pb, Ql + pb, Kh + pb, Kl + pb, Vth + pb};
#pragma unroll
    for (int pl = 0; pl < 5; ++pl)
        ((float4v*)dsts[pl])[tid] = ((const float4v*)(sBlob + pl * 4096))[tid];

    if (e == 0) {
        int tok4 = tid >> 2;
        int m0   = (tid & 3) * 8;
        int t = b * Tv + tile * 64 + tok4;
        const float4v* xr = (const float4v*)(x + (size_t)t * INv);
        float qm[8];
#pragma unroll
        for (int m = 0; m < 8; ++m) qm[m] = 0.f;
#pragma unroll
        for (int i4 = 0; i4 < 8; ++i4) {
            float4v xv = __builtin_nontemporal_load(&xr[i4]);
            float xs[4] = {xv.x, xv.y, xv.z, xv.w};
#pragma unroll
            for (int s = 0; s < 4; ++s) {
                int i = i4 * 4 + s;
                float xi = xs[s];
                float4v w0 = *(const float4v*)&sIQ[i][m0];
                float4v w1 = *(const float4v*)&sIQ[i][m0 + 4];
                qm[0] = fmaf(xi, w0.x, qm[0]); qm[1] = fmaf(xi, w0.y, qm[1]);
                qm[2] = fmaf(xi, w0.z, qm[2]); qm[3] = fmaf(xi, w0.w, qm[3]);
                qm[4] = fmaf(xi, w1.x, qm[4]); qm[5] = fmaf(xi, w1.y, qm[5]);
                qm[6] = fmaf(xi, w1.z, qm[6]); qm[7] = fmaf(xi, w1.w, qm[7]);
            }
        }
        float sc[20];
#pragma unroll
        for (int j = 0; j < 20; ++j) {
            float4v s0 = *(const float4v*)&sM[j][m0];
            float4v s1 = *(const float4v*)&sM[j][m0 + 4];
            float a2 = qm[0]*s0.x + qm[1]*s0.y + qm[2]*s0.z + qm[3]*s0.w
                     + qm[4]*s1.x + qm[5]*s1.y + qm[6]*s1.z + qm[7]*s1.w;
            a2 += __shfl_xor(a2, 1);
            a2 += __shfl_xor(a2, 2);
            sc[j] = a2;
        }
        float mx = sc[0];
#pragma unroll
        for (int j = 1; j < 20; ++j) mx = fmaxf(mx, sc[j]);
        float psum = 0.f, p[20];
#pragma unroll
        for (int j = 0; j < 20; ++j) { p[j] = exp2f((sc[j] - mx) * LOG2E); psum += p[j]; }
        float inv = 1.0f / psum;
        float mo[8];
#pragma unroll
        for (int m = 0; m < 8; ++m) mo[m] = 0.f;
#pragma unroll
        for (int j = 0; j < 20; ++j) {
            float pj = p[j];
            float4v s0 = *(const float4v*)&sM[j][m0];
            float4v s1 = *(const float4v*)&sM[j][m0 + 4];
            mo[0] = fmaf(pj, s0.x, mo[0]); mo[1] = fmaf(pj, s0.y, mo[1]);
            mo[2] = fmaf(pj, s0.z, mo[2]); mo[3] = fmaf(pj, s0.w, mo[3]);
            mo[4] = fmaf(pj, s1.x, mo[4]); mo[5] = fmaf(pj, s1.y, mo[5]);
            mo[6] = fmaf(pj, s1.z, mo[6]); mo[7] = fmaf(pj, s1.w, mo[7]);
        }
        float4v* outp = (float4v*)(memout + (size_t)t * Mv + m0);
        float4v o0 = {mo[0]*inv, mo[1]*inv, mo[2]*inv, mo[3]*inv};
        float4v o1 = {mo[4]*inv, mo[5]*inv, mo[6]*inv, mo[7]*inv};
        outp[0] = o0;
        outp[1] = o1;
    }
}

// ---------------------------------------------------------------------------
// Kernel 2: register-resident flash attention + tile-skip (R5 structure =
// best measured 58.9us; R7's 4-deep pipeline regressed and is reverted).
// R9: only change vs R5 = memv epilogue operands prefetched at kernel entry
// (miss latency overlaps the 32-chunk main loop).
// ---------------------------------------------------------------------------
#define ATT_LOAD(c, KH, KL, V0, V1)                                           \
    {                                                                         \
        size_t ko = ebOff + (size_t)((c) * 64 + w * 16 + l15) * 32 + quad * 8;\
        KH = *(const half8*)(Kh + ko);                                        \
        KL = *(const half8*)(Kl + ko);                                        \
        size_t vo = ebOff + (size_t)(c) * 2048 + (size_t)l15 * 64             \
                    + w * 16 + quad * 4;                                      \
        V0 = *(const half4v*)(Vth + vo);                                      \
        V1 = *(const half4v*)(Vth + vo + 1024);                               \
    }

#define ATT_BODY(KH, KL, V0, V1)                                              \
    _Pragma("unroll")                                                         \
    for (int qt = 0; qt < 4; ++qt) {                                          \
        float4v acc = {0.f, 0.f, 0.f, 0.f};                                   \
        acc = __builtin_amdgcn_mfma_f32_16x16x32_f16(KH, qL[qt], acc, 0,0,0); \
        acc = __builtin_amdgcn_mfma_f32_16x16x32_f16(KL, qH[qt], acc, 0,0,0); \
        acc = __builtin_amdgcn_mfma_f32_16x16x32_f16(KH, qH[qt], acc, 0,0,0); \
        float pmax4 = fmaxf(fmaxf(acc[0], acc[1]), fmaxf(acc[2], acc[3]));    \
        if (!__any(pmax4 > mm[qt] - 20.0f)) continue;   /* tile irrelevant */ \
        if (__any(pmax4 > mm[qt] + 8.0f)) {             /* rare rescale */    \
            float pm = fmaxf(pmax4, __shfl_xor(pmax4, 16));                   \
            pm = fmaxf(pm, __shfl_xor(pm, 32));                               \
            float mn = fmaxf(mm[qt], pm);                                     \
            float al = exp2f(mm[qt] - mn);                                    \
            mm[qt] = mn;                                                      \
            _Pragma("unroll")                                                 \
            for (int r = 0; r < 4; ++r) {                                     \
                O[qt][0][r] *= al; O[qt][1][r] *= al;                         \
            }                                                                 \
        }                                                                     \
        fp16x2 p01 = __builtin_amdgcn_cvt_pkrtz(exp2f(acc[0] - mm[qt]),       \
                                                exp2f(acc[1] - mm[qt]));      \
        fp16x2 p23 = __builtin_amdgcn_cvt_pkrtz(exp2f(acc[2] - mm[qt]),       \
                                                exp2f(acc[3] - mm[qt]));      \
        unsigned long long up =                                               \
            ((unsigned long long)__builtin_bit_cast(unsigned int, p23) << 32) \
            | __builtin_bit_cast(unsigned int, p01);                          \
        half4v pB = __builtin_bit_cast(half4v, up);                           \
        O[qt][0] = __builtin_amdgcn_mfma_f32_16x16x16f16(V0, pB, O[qt][0],    \
                                                         0, 0, 0);            \
        O[qt][1] = __builtin_amdgcn_mfma_f32_16x16x16f16(V1, pB, O[qt][1],    \
                                                         0, 0, 0);            \
    }

__global__ __launch_bounds__(256, 3) void attn_kernel(
    const _Float16* __restrict__ Qh, const _Float16* __restrict__ Ql,
    const _Float16* __restrict__ Kh, const _Float16* __restrict__ Kl,
    const _Float16* __restrict__ Vth,
    const float* __restrict__ memv,
    float* __restrict__ out)
{
    __shared__ float sO[4][64][33];     // padded: +1 breaks bank conflicts
    __shared__ float sMw[4][64];

    int bid  = blockIdx.x;              // 768
    int xcd  = bid & 7;
    int slot = bid >> 3;
    int tile = slot & 31;
    int ebi  = xcd + ((slot >> 5) << 3);
    int e    = ebi >> 3;
    int b    = ebi & 7;
    int tid  = threadIdx.x;
    int lane = tid & 63;
    int w    = tid >> 6;
    int quad = lane >> 4;
    int l15  = lane & 15;
    size_t eb = (size_t)ebi;
    size_t ebOff = eb * (size_t)Tv * 32;

    // Epilogue operand prefetch (miss latency overlaps the main loop)
    const float* mbp = memv + ((size_t)b * Tv + tile * 64 + (tid >> 2)) * 32
                       + (tid & 3) * 8;
    float4v mpre0 = *(const float4v*)(mbp);
    float4v mpre1 = *(const float4v*)(mbp + 4);

    // Q fragments (B operand: col=q=l15, k=h=quad*8+i): 4 q-tiles x hi/lo
    half8 qH[4], qL[4];
#pragma unroll
    for (int qt = 0; qt < 4; ++qt) {
        size_t qoff = ebOff + (size_t)(tile * 64 + qt * 16 + l15) * 32 + quad * 8;
        qH[qt] = *(const half8*)(Qh + qoff);
        qL[qt] = *(const half8*)(Ql + qoff);
    }

    float4v O[4][2];                    // O^T[d][q]: d=dh*16+quad*4+r, q=l15
#pragma unroll
    for (int qt = 0; qt < 4; ++qt) {
        O[qt][0] = {0.f, 0.f, 0.f, 0.f};
        O[qt][1] = {0.f, 0.f, 0.f, 0.f};
    }
    float mm[4] = {-3.0e38f, -3.0e38f, -3.0e38f, -3.0e38f};

    half8 kHa, kLa, kHb, kLb;
    half4v v0a, v1a, v0b, v1b;
    ATT_LOAD(0, kHa, kLa, v0a, v1a);

    for (int c = 0; c < 32; c += 2) {
        ATT_LOAD(c + 1, kHb, kLb, v0b, v1b);
        ATT_BODY(kHa, kLa, v0a, v1a);
        if (c + 2 < 32) ATT_LOAD(c + 2, kHa, kLa, v0a, v1a);
        ATT_BODY(kHb, kLb, v0b, v1b);
    }

    // ---- merge 4 per-wave partials (single barrier in whole kernel)
#pragma unroll
    for (int qt = 0; qt < 4; ++qt) {
        int q = qt * 16 + l15;
        sMw[w][q] = mm[qt];
#pragma unroll
        for (int dh = 0; dh < 2; ++dh)
#pragma unroll
            for (int r = 0; r < 4; ++r)
                sO[w][q][dh * 16 + quad * 4 + r] = O[qt][dh][r];
    }
    __syncthreads();

    int q  = tid >> 2;
    int dq = tid & 3;
    float ms0 = sMw[0][q], ms1 = sMw[1][q], ms2 = sMw[2][q], ms3 = sMw[3][q];
    float M  = fmaxf(fmaxf(ms0, ms1), fmaxf(ms2, ms3));
    float g0 = exp2f(ms0 - M), g1 = exp2f(ms1 - M);
    float g2 = exp2f(ms2 - M), g3 = exp2f(ms3 - M);
    float mv8[8] = {mpre0.x, mpre0.y, mpre0.z, mpre0.w,
                    mpre1.x, mpre1.y, mpre1.z, mpre1.w};
    float dotm = 0.f, oo = 0.f, mm2 = 0.f;
#pragma unroll
    for (int j = 0; j < 8; ++j) {
        int d = dq * 8 + j;
        float o = g0 * sO[0][q][d] + g1 * sO[1][q][d]
                + g2 * sO[2][q][d] + g3 * sO[3][q][d];
        float mvv = mv8[j];
        dotm = fmaf(o, mvv, dotm);
        oo   = fmaf(o, o, oo);
        mm2  = fmaf(mvv, mvv, mm2);
    }
    dotm += __shfl_xor(dotm, 1); dotm += __shfl_xor(dotm, 2);
    oo   += __shfl_xor(oo, 1);   oo   += __shfl_xor(oo, 2);
    mm2  += __shfl_xor(mm2, 1);  mm2  += __shfl_xor(mm2, 2);
    if (dq == 0) {
        float na = fmaxf(sqrtf(mm2), 1e-8f);
        float nb = fmaxf(sqrtf(oo), 1e-30f);
        out[((size_t)b * Tv + tile * 64 + q) * Ev + e] = dotm / (na * nb);
    }
}

// ---------------------------------------------------------------------------
extern "C" void kernel_launch(void* const* d_in, const int* in_sizes, int n_in,
                              void* d_out, int out_size, void* d_ws, size_t ws_size,
                              hipStream_t stream) {
    const float* x      = (const float*)d_in[0];
    const float* hidden = (const float*)d_in[1];
    const float* memory = (const float*)d_in[2];
    const float* Wq     = (const float*)d_in[3];
    const float* Wk     = (const float*)d_in[4];
    const float* Wv     = (const float*)d_in[5];
    const float* iq     = (const float*)d_in[6];
    float* out          = (float*)d_out;           // [B,T,E] fp32

    char* ws = (char*)d_ws;
    // layout (bytes): memout f32 (2 MiB) | 5 f16 planes a 3 MiB = 17 MiB
    const size_t PLANE = (size_t)Ev * Bv * Tv * 32 * 2;   // 3,145,728 B
    float*    memout = (float*)ws;
    _Float16* Qh  = (_Float16*)(ws + 2097152);
    _Float16* Ql  = (_Float16*)(ws + 2097152 + PLANE);
    _Float16* Kh  = (_Float16*)(ws + 2097152 + 2 * PLANE);
    _Float16* Kl  = (_Float16*)(ws + 2097152 + 3 * PLANE);
    _Float16* Vth = (_Float16*)(ws + 2097152 + 4 * PLANE);

    qkv_kernel<<<Ev * Bv * (Tv / 64), 256, 0, stream>>>(hidden, Wq, Wk, Wv,
                                                        x, memory, iq,
                                                        Qh, Ql, Kh, Kl, Vth, memout);
    attn_kernel<<<Ev * Bv * (Tv / 64), 256, 0, stream>>>(Qh, Ql, Kh, Kl, Vth,
                                                         memout, out);
}